// Round 3
// baseline (81.786 us; speedup 1.0000x reference)
//
#include <hip/hip_runtime.h>
#include <math.h>

#define FAR_DELTA 1e10f
#define TRANS_EPS 1e-10f
#define RPB 16   // rays per block
#define S  48    // samples per ray

// DPP move: returns src moved per CTRL; invalid source lanes yield `old`.
template<int CTRL>
__device__ __forceinline__ float dppf(float x, float old) {
    return __int_as_float(__builtin_amdgcn_update_dpp(
        __float_as_int(old), __float_as_int(x), CTRL, 0xF, 0xF, false));
}

// 16 lanes per ray (one DPP row), 3 samples per lane, 16 rays per 256-thr block.
// All global traffic is linear float4 through LDS.
__global__ __launch_bounds__(256) void nerf_render_kernel(
    const float* __restrict__ xyz,   // [N, 48, 3]
    const float* __restrict__ dens,  // [N, 48]
    const float* __restrict__ rgb,   // [N, 48, 3]
    const float* __restrict__ bg,    // [N, 3]
    float* __restrict__ out_rgb,     // [N, 3]
    float* __restrict__ out_acc,     // [N]
    float* __restrict__ out_w,       // [N, 48]
    int N)
{
    __shared__ float s_xyz[RPB * S * 3];   // 2304 floats, 9216 B
    __shared__ float s_rgb[RPB * S * 3];   // 9216 B
    __shared__ float s_den[RPB * S];       // 3072 B; reused for weights
    __shared__ float s_bg [RPB * 3];       // 192 B
    __shared__ float s_or [RPB * 3];       // out rgb staging
    __shared__ float s_oa [RPB];           // out acc staging

    const int t    = threadIdx.x;
    const int ray0 = blockIdx.x * RPB;
    const int nray = min(RPB, N - ray0);

    if (nray == RPB) {
        // ---- fast path: full block, float4 staging ----
        const float4* gx = (const float4*)(xyz  + (size_t)ray0 * (S * 3));
        const float4* gc = (const float4*)(rgb  + (size_t)ray0 * (S * 3));
        const float4* gd = (const float4*)(dens + (size_t)ray0 * S);
        const float4* gb = (const float4*)(bg   + (size_t)ray0 * 3);
        float4* sx = (float4*)s_xyz;
        float4* sc = (float4*)s_rgb;
        float4* sd = (float4*)s_den;
        float4* sb = (float4*)s_bg;
        sx[t]       = gx[t];
        sx[t + 256] = gx[t + 256];
        sc[t]       = gc[t];
        sc[t + 256] = gc[t + 256];
        if (t < 64)  { sx[t + 512] = gx[t + 512]; sc[t + 512] = gc[t + 512]; }
        if (t < 192) sd[t] = gd[t];
        if (t < 12)  sb[t] = gb[t];
    } else {
        // ---- tail path: scalar staging with bounds ----
        const int nf3 = nray * S * 3, nf1 = nray * S, nfb = nray * 3;
        for (int i = t; i < nf3; i += 256) s_xyz[i] = xyz[(size_t)ray0 * (S*3) + i];
        for (int i = t; i < nf3; i += 256) s_rgb[i] = rgb[(size_t)ray0 * (S*3) + i];
        for (int i = t; i < nf1; i += 256) s_den[i] = dens[(size_t)ray0 * S + i];
        for (int i = t; i < nfb; i += 256) s_bg[i]  = bg[(size_t)ray0 * 3 + i];
    }
    __syncthreads();

    const int g  = t >> 4;    // ray within block (aligned to DPP rows)
    const int li = t & 15;    // lane within ray

    if (g < nray) {
        const float* px = s_xyz + g * (S * 3) + li * 9;
        float x0 = px[0], y0 = px[1], z0 = px[2];
        float x1 = px[3], y1 = px[4], z1 = px[5];
        float x2 = px[6], y2 = px[7], z2 = px[8];

        const float* pd = s_den + g * S + li * 3;
        float d0 = pd[0], d1 = pd[1], d2 = pd[2];

        const float* pc = s_rgb + g * (S * 3) + li * 9;
        float r0 = pc[0], g0 = pc[1], b0 = pc[2];
        float r1 = pc[3], g1 = pc[4], b1 = pc[5];
        float r2 = pc[6], g2 = pc[7], b2 = pc[8];

        // next lane's first sample position (row_shl:1)
        float xn = dppf<0x101>(x0, 0.f);
        float yn = dppf<0x101>(y0, 0.f);
        float zn = dppf<0x101>(z0, 0.f);

        float dx, dy, dz;
        dx = x1 - x0; dy = y1 - y0; dz = z1 - z0;
        float delta0 = sqrtf(dx * dx + dy * dy + dz * dz);
        dx = x2 - x1; dy = y2 - y1; dz = z2 - z1;
        float delta1 = sqrtf(dx * dx + dy * dy + dz * dz);
        float delta2;
        if (li == 15) {
            delta2 = FAR_DELTA;
        } else {
            dx = xn - x2; dy = yn - y2; dz = zn - z2;
            delta2 = sqrtf(dx * dx + dy * dy + dz * dz);
        }

        float e0 = __expf(-fmaxf(d0, 0.f) * delta0);
        float e1 = __expf(-fmaxf(d1, 0.f) * delta1);
        float e2 = __expf(-fmaxf(d2, 0.f) * delta2);
        float a0 = 1.f - e0, a1 = 1.f - e1, a2 = 1.f - e2;
        float q0 = e0 + TRANS_EPS, q1 = e1 + TRANS_EPS, q2 = e2 + TRANS_EPS;

        // exclusive product scan of m = q0*q1*q2 across the 16-lane row
        float m = q0 * q1 * q2;
        float tr = dppf<0x111>(m, 1.f);    // row_shr:1 (lane0 -> 1)
        tr *= dppf<0x111>(tr, 1.f);
        tr *= dppf<0x112>(tr, 1.f);
        tr *= dppf<0x114>(tr, 1.f);
        tr *= dppf<0x118>(tr, 1.f);

        float T0 = tr, T1 = tr * q0, T2 = T1 * q1;
        float w0 = a0 * T0, w1 = a1 * T1, w2 = a2 * T2;

        // weights back into the (now dead) density slots — same lane, same addrs
        float* pw = s_den + g * S + li * 3;
        pw[0] = w0; pw[1] = w1; pw[2] = w2;

        float sr = w0 * r0 + w1 * r1 + w2 * r2;
        float sg = w0 * g0 + w1 * g1 + w2 * g2;
        float sb = w0 * b0 + w1 * b1 + w2 * b2;
        float sw = w0 + w1 + w2;

        sr += dppf<0xB1>(sr, 0.f);  sg += dppf<0xB1>(sg, 0.f);
        sb += dppf<0xB1>(sb, 0.f);  sw += dppf<0xB1>(sw, 0.f);
        sr += dppf<0x4E>(sr, 0.f);  sg += dppf<0x4E>(sg, 0.f);
        sb += dppf<0x4E>(sb, 0.f);  sw += dppf<0x4E>(sw, 0.f);
        sr += dppf<0x141>(sr, 0.f); sg += dppf<0x141>(sg, 0.f);
        sb += dppf<0x141>(sb, 0.f); sw += dppf<0x141>(sw, 0.f);
        sr += dppf<0x140>(sr, 0.f); sg += dppf<0x140>(sg, 0.f);
        sb += dppf<0x140>(sb, 0.f); sw += dppf<0x140>(sw, 0.f);

        if (li == 0) {
            float inv = 1.f - sw;
            s_or[g * 3 + 0] = sr + s_bg[g * 3 + 0] * inv;
            s_or[g * 3 + 1] = sg + s_bg[g * 3 + 1] * inv;
            s_or[g * 3 + 2] = sb + s_bg[g * 3 + 2] * inv;
            s_oa[g] = sw;
        }
    }
    __syncthreads();

    if (nray == RPB) {
        // ---- coalesced float4 output ----
        float4* gw = (float4*)(out_w + (size_t)ray0 * S);
        if (t < 192) gw[t] = ((const float4*)s_den)[t];
        float4* gr = (float4*)(out_rgb + (size_t)ray0 * 3);
        if (t < 12) gr[t] = ((const float4*)s_or)[t];
        float4* ga = (float4*)(out_acc + ray0);
        if (t < 4) ga[t] = ((const float4*)s_oa)[t];
    } else {
        const int nw = nray * S, no = nray * 3;
        for (int i = t; i < nw; i += 256) out_w[(size_t)ray0 * S + i] = s_den[i];
        for (int i = t; i < no; i += 256) out_rgb[(size_t)ray0 * 3 + i] = s_or[i];
        for (int i = t; i < nray; i += 256) out_acc[ray0 + i] = s_oa[i];
    }
}

extern "C" void kernel_launch(void* const* d_in, const int* in_sizes, int n_in,
                              void* d_out, int out_size, void* d_ws, size_t ws_size,
                              hipStream_t stream) {
    const float* xyz  = (const float*)d_in[0];   // [N,48,3]
    const float* dens = (const float*)d_in[1];   // [N,48,1]
    const float* rgb  = (const float*)d_in[2];   // [N,48,3]
    const float* bg   = (const float*)d_in[3];   // [N,3]

    const int N = in_sizes[3] / 3;               // S = 48

    float* out     = (float*)d_out;
    float* out_rgb = out;                  // N*3
    float* out_acc = out + (size_t)N * 3;  // N
    float* out_w   = out + (size_t)N * 4;  // N*48

    const int grid = (N + RPB - 1) / RPB;
    nerf_render_kernel<<<grid, 256, 0, stream>>>(xyz, dens, rgb, bg,
                                                 out_rgb, out_acc, out_w, N);
}